// Round 21
// baseline (233.616 us; speedup 1.0000x reference)
//
#include <hip/hip_runtime.h>
#include <hip/hip_bf16.h>

// MultiHeadAttention: B=2, S=2048, H=1024, NH=16, DK=64
// R21: R20 (best: 226.3 us) with k_combine DELETED — the out-GEMM (MODE 1)
// A-stage now reads both bf16 partial-O halves + (m,l) and combines in
// registers, ds_write_b128 into the same swizzled As layout. One fewer
// launch + no ctx round-trip. Sync structure of the GEMM unchanged
// (__syncthreads pair drains both ds_write and gl_lds staging).

#define S_LEN 2048
#define H_DIM 1024
#define N_HEADS 16

typedef __bf16 bf16x8 __attribute__((ext_vector_type(8)));
typedef __bf16 bf16x4 __attribute__((ext_vector_type(4)));
typedef float f32x4 __attribute__((ext_vector_type(4)));
typedef unsigned long long u64;

using gvoid = __attribute__((address_space(1))) void;
using svoid = __attribute__((address_space(3))) void;

static __device__ __forceinline__ f32x4 mfma16(bf16x8 a, bf16x8 b, f32x4 c) {
  return __builtin_amdgcn_mfma_f32_16x16x32_bf16(a, b, c, 0, 0, 0);
}

// Stage a [ROWS][64] bf16 tile into LDS via global_load_lds, 16B per lane.
// LDS: linear rows of 128B; 16B slot s holds global slot s^(r&7) (bank swizzle).
template <int NCH, int NW>
static __device__ __forceinline__ void stage64(const __bf16* g, int rstride,
                                               __bf16* lds, int wid, int lane) {
#pragma unroll
  for (int i = 0; i < NCH / NW; ++i) {
    int chunk = i * NW + wid;
    int u = chunk * 64 + lane;
    int r = u >> 3, s = u & 7;
    const __bf16* src = g + (size_t)r * rstride + ((s ^ (r & 7)) << 3);
    __builtin_amdgcn_global_load_lds((const gvoid*)src,
                                     (svoid*)(lds + chunk * 512), 16, 0, 0);
  }
}

static __device__ __forceinline__ bf16x8 read_frag(const __bf16* lds, int r,
                                                   int slot) {
  return *(const bf16x8*)(lds + r * 64 + ((slot ^ (r & 7)) << 3));
}

// ---------------- prep: x -> bf16 | mask -> u64 bits | W -> W^T bf16
__global__ __launch_bounds__(256) void k_prep(
    const float* __restrict__ x, __bf16* __restrict__ xb,
    const int* __restrict__ m, u64* __restrict__ mout,
    const float* __restrict__ w0, const float* __restrict__ w1,
    const float* __restrict__ w2, const float* __restrict__ w3,
    __bf16* __restrict__ wt) {
  int blk = blockIdx.x;
  if (blk < 2048) {
    size_t idx = ((size_t)blk * 256 + threadIdx.x) * 8;
    float4 a = *(const float4*)(x + idx);
    float4 b = *(const float4*)(x + idx + 4);
    bf16x8 o;
    o[0] = (__bf16)a.x; o[1] = (__bf16)a.y; o[2] = (__bf16)a.z; o[3] = (__bf16)a.w;
    o[4] = (__bf16)b.x; o[5] = (__bf16)b.y; o[6] = (__bf16)b.z; o[7] = (__bf16)b.w;
    *(bf16x8*)(xb + idx) = o;
  } else if (blk < 34816) {
    size_t idx = (size_t)(blk - 2048) * 256 + threadIdx.x;
    u64 b = __ballot(m[idx] != 0);
    if ((threadIdx.x & 63) == 0) mout[idx >> 6] = b;
  } else {
    __shared__ float t[64][65];
    int i = blk - 34816;
    int z = i >> 8;
    const float* W = (z == 0) ? w0 : (z == 1) ? w1 : (z == 2) ? w2 : w3;
    __bf16* O = wt + (size_t)z * H_DIM * H_DIM;
    int k0 = ((i >> 4) & 15) * 64, n0 = (i & 15) * 64;
    int tid = threadIdx.x;
    {
      int r = tid >> 4, c4 = tid & 15;
#pragma unroll
      for (int j = 0; j < 4; ++j) {
        float4 v =
            *(const float4*)(W + (size_t)(k0 + r + j * 16) * H_DIM + n0 + c4 * 4);
        t[r + j * 16][c4 * 4 + 0] = v.x;
        t[r + j * 16][c4 * 4 + 1] = v.y;
        t[r + j * 16][c4 * 4 + 2] = v.z;
        t[r + j * 16][c4 * 4 + 3] = v.w;
      }
    }
    __syncthreads();
    {
      int nn = tid >> 2, js = (tid & 3) * 16;
      bf16x8 o0, o1;
#pragma unroll
      for (int j = 0; j < 8; ++j) {
        o0[j] = (__bf16)t[js + j][nn];
        o1[j] = (__bf16)t[js + 8 + j][nn];
      }
      __bf16* dst = O + (size_t)(n0 + nn) * H_DIM + k0 + js;
      *(bf16x8*)dst = o0;
      *(bf16x8*)(dst + 8) = o1;
    }
  }
}

// ----------------------------------------------------------------- GEMMs
// MODE 0: C = xb . Wt^T + bias -> bf16; z==0 (Q, scaled 1/8) and z==1 (K)
//         write [b,h,s,d]; z==2 (V) writes V^T [b,h,d,s] directly.
// MODE 1: A is built on the fly from bf16 partial-O halves + (m,l)
//         (combine fold); C = combined-ctx . Wt_o^T + bias -> f32 out.
template <int MODE>
__global__ __launch_bounds__(256) void k_gemm(
    const __bf16* __restrict__ A, const __bf16* __restrict__ B0,
    const __bf16* __restrict__ B1, const __bf16* __restrict__ B2,
    const float* __restrict__ bias0, const float* __restrict__ bias1,
    const float* __restrict__ bias2, __bf16* __restrict__ O0,
    __bf16* __restrict__ O1, __bf16* __restrict__ O2, float* __restrict__ Of,
    const __bf16* __restrict__ OpA, const float* __restrict__ mlA) {
  __shared__ alignas(16) __bf16 As[128 * 64];
  __shared__ alignas(16) __bf16 Bs[128 * 64];
  int tid = threadIdx.x, wid = tid >> 6, lane = tid & 63;
  int l15 = lane & 15, lg = lane >> 4;
  int nbase = blockIdx.x * 128, mbase = blockIdx.y * 128;
  const __bf16* Bm;
  const float* bias;
  __bf16* Ob;
  float oscale = 1.0f;
  const int zv = (MODE == 0) ? blockIdx.z : 0;
  if (MODE == 0) {
    Bm = (zv == 0) ? B0 : (zv == 1) ? B1 : B2;
    bias = (zv == 0) ? bias0 : (zv == 1) ? bias1 : bias2;
    Ob = (zv == 0) ? O0 : (zv == 1) ? O1 : O2;
    if (zv == 0) oscale = 0.125f;
  } else {
    Bm = B0; bias = bias0; Ob = O0;
  }
  int wrow = wid >> 1, wcol = wid & 1;
  f32x4 zero = {0.f, 0.f, 0.f, 0.f};
  f32x4 acc[4][4];
#pragma unroll
  for (int i = 0; i < 4; ++i)
#pragma unroll
    for (int j = 0; j < 4; ++j) acc[i][j] = zero;

  for (int kb = 0; kb < H_DIM; kb += 64) {
    __syncthreads();
    if (MODE == 0) {
      stage64<16, 4>(A + (size_t)mbase * H_DIM + kb, H_DIM, As, wid, lane);
    } else {
      // combine-fold: build As[128][64] (swizzled: physical slot s holds
      // logical slot s^(r&7)) from the two bf16 partial-O halves + (m,l).
      int bb = mbase >> 11, q0 = mbase & 2047, head = kb >> 6;
      size_t bho_ = (size_t)bb * N_HEADS + head;
      const __bf16* op0 = OpA + (bho_ * S_LEN + q0) * 64;
      const __bf16* op1 = OpA + (((size_t)32 + bho_) * S_LEN + q0) * 64;
      const float* ml0 = mlA + (bho_ * S_LEN + q0) * 2;
      const float* ml1 = mlA + (((size_t)32 + bho_) * S_LEN + q0) * 2;
#pragma unroll
      for (int i = 0; i < 4; ++i) {
        int chunk = i * 4 + wid;
        int u = chunk * 64 + lane;
        int r = u >> 3, s = u & 7;
        int slot = (s ^ (r & 7)) << 3;
        bf16x8 a = *(const bf16x8*)(op0 + (size_t)r * 64 + slot);
        bf16x8 c = *(const bf16x8*)(op1 + (size_t)r * 64 + slot);
        float2 m0 = *(const float2*)(ml0 + r * 2);
        float2 m1 = *(const float2*)(ml1 + r * 2);
        float mm = fmaxf(m0.x, m1.x);
        float e0 = __expf(m0.x - mm), e1 = __expf(m1.x - mm);
        float inv = 1.f / (m0.y * e0 + m1.y * e1);
        e0 *= inv;
        e1 *= inv;
        bf16x8 o;
#pragma unroll
        for (int j = 0; j < 8; ++j)
          o[j] = (__bf16)((float)a[j] * e0 + (float)c[j] * e1);
        *(bf16x8*)(As + chunk * 512 + lane * 8) = o;
      }
    }
    stage64<16, 4>(Bm + (size_t)nbase * H_DIM + kb, H_DIM, Bs, wid, lane);
    __syncthreads();
#pragma unroll
    for (int t = 0; t < 2; ++t) {
      bf16x8 a[4], bfr[4];
#pragma unroll
      for (int i = 0; i < 4; ++i)
        a[i] = read_frag(As, wrow * 64 + i * 16 + l15, t * 4 + lg);
#pragma unroll
      for (int j = 0; j < 4; ++j)
        bfr[j] = read_frag(Bs, wcol * 64 + j * 16 + l15, t * 4 + lg);
#pragma unroll
      for (int i = 0; i < 4; ++i)
#pragma unroll
        for (int j = 0; j < 4; ++j) acc[i][j] = mfma16(a[i], bfr[j], acc[i][j]);
    }
  }
  float bv[4];
#pragma unroll
  for (int j = 0; j < 4; ++j) bv[j] = bias[nbase + wcol * 64 + j * 16 + l15];
#pragma unroll
  for (int i = 0; i < 4; ++i)
#pragma unroll
    for (int j = 0; j < 4; ++j) {
      if (MODE == 0 && zv == 2) {
        // V^T direct: the 4 r-values are 4 consecutive s at fixed col=d.
        int m0 = mbase + wrow * 64 + i * 16 + lg * 4;
        int col = nbase + wcol * 64 + j * 16 + l15;
        bf16x4 u;
#pragma unroll
        for (int r = 0; r < 4; ++r) u[r] = (__bf16)(acc[i][j][r] + bv[j]);
        size_t off =
            (((size_t)(m0 >> 11) * N_HEADS + (col >> 6)) * 64 + (col & 63)) *
                (size_t)S_LEN +
            (m0 & 2047);
        *(bf16x4*)(Ob + off) = u;
      } else {
#pragma unroll
        for (int r = 0; r < 4; ++r) {
          int m = mbase + wrow * 64 + i * 16 + lg * 4 + r;
          int col = nbase + wcol * 64 + j * 16 + l15;
          float v = (acc[i][j][r] + bv[j]) * oscale;
          if (MODE == 0) {
            size_t off =
                (((size_t)(m >> 11) * N_HEADS + (col >> 6)) * S_LEN +
                 (m & 2047)) *
                    64 +
                (col & 63);
            Ob[off] = (__bf16)v;
          } else {
            Of[(size_t)m * H_DIM + col] = v;
          }
        }
      }
    }
}

// ------------------------------------------------------------- attention
// R20 kernel verbatim: KV-split x2, in-place softmax, XCD alibi pairing
// (b=bh>>4, h=bh&15). grid: (B*NH, S/128, 2); block 512 (8 waves).
// Two-barrier counted-vmcnt skeleton. Emits bf16 partial O + f32 (m,l).
__global__ __launch_bounds__(512) void k_attn(
    const __bf16* __restrict__ Q, const __bf16* __restrict__ K,
    const __bf16* __restrict__ VT, const float* __restrict__ alibi,
    const u64* __restrict__ maskb, __bf16* __restrict__ Op,
    float* __restrict__ ml) {
  __shared__ alignas(16) __bf16 Ks[2][64 * 64];
  __shared__ alignas(16) __bf16 Vs[64 * 64];
  __shared__ alignas(16) __bf16 Ps[8][16 * 72];
  int tid = threadIdx.x, wid = tid >> 6, lane = tid & 63;
  int l15 = lane & 15, lg = lane >> 4;
  int bh = blockIdx.x;
  int b = bh >> 4, h = bh & 15;  // pair (b0,b1) of one h: x=h and x=h+16
  int qbase = blockIdx.y * 128;  // -> same XCD (x mod 8 equal), same rows
  const int z = blockIdx.z;
  size_t bho = (size_t)(b * N_HEADS + h);
  const __bf16* Qb = Q + bho * S_LEN * 64;
  const __bf16* Kbz = K + (bho * S_LEN + (size_t)z * 1024) * 64;
  const __bf16* Vbz = VT + bho * 64 * S_LEN + z * 1024;
  const int q = qbase + wid * 16 + l15;  // this lane's q row
  const int NT = 16;                     // 1024 k-positions per half

  bf16x8 qa[2];
  {
    const __bf16* qrow = Qb + (size_t)q * 64;
    qa[0] = *(const bf16x8*)(qrow + lg * 8);
    qa[1] = *(const bf16x8*)(qrow + 32 + lg * 8);
  }
  float mrun = -__builtin_inff(), lrun = 0.f;
  f32x4 cacc[4];  // O^T[d = c*16+lg*4+r][q = l15]
  f32x4 zero = {0.f, 0.f, 0.f, 0.f};
#pragma unroll
  for (int c = 0; c < 4; ++c) cacc[c] = zero;

  const float* arow =
      alibi + ((size_t)h * S_LEN + q) * S_LEN + z * 1024 + lg * 4;
  const u64* mrow =
      maskb + ((size_t)b * S_LEN + q) * (S_LEN / 64) + z * 16;

  // ---- prologue: K(0) stage, alibi(0)+mask(0) regs (order pinned) ----
  stage64<8, 8>(Kbz, 64, Ks[0], wid, lane);  // 1 gl_lds
  __builtin_amdgcn_sched_barrier(0);
  f32x4 albP[4];
  u64 mskP;
#pragma unroll
  for (int c = 0; c < 4; ++c) albP[c] = *(const f32x4*)(arow + c * 16);  // 4
  mskP = mrow[0];                                                        // 1
  __builtin_amdgcn_sched_barrier(0);

  for (int t = 0; t < NT; ++t) {
    const int cur = t & 1;
    // E: K(t) complete (5 newer in flight: alibi(t) 4 + mask(t) 1)
    asm volatile("s_waitcnt vmcnt(5)" ::: "memory");
    __builtin_amdgcn_sched_barrier(0);
    __builtin_amdgcn_s_barrier();
    __builtin_amdgcn_sched_barrier(0);
    // A: stage V(t) (consumed after F this phase; Vs free since barrier)
    stage64<8, 8>(Vbz + t * 64, S_LEN, Vs, wid, lane);  // 1
    __builtin_amdgcn_sched_barrier(0);
    // B: stage K(t+1) into alternate buffer (clamped at the end)
    const int tn = (t + 1 < NT) ? t + 1 : t;
    stage64<8, 8>(Kbz + (size_t)tn * 64 * 64, 64, Ks[cur ^ 1], wid, lane);  // 1
    __builtin_amdgcn_sched_barrier(0);

    // QK^T swapped: sacc[c][r] = S[k=c*16+lg*4+r][q=l15] + alibi (C-init).
    // (Q pre-scaled by 1/8 in the QKV GEMM epilogue.)
    f32x4 sacc[4];
#pragma unroll
    for (int c = 0; c < 4; ++c) sacc[c] = albP[c];
    __builtin_amdgcn_s_setprio(1);
#pragma unroll
    for (int t2 = 0; t2 < 2; ++t2) {
      bf16x8 kf[4];
#pragma unroll
      for (int c = 0; c < 4; ++c)
        kf[c] = read_frag(Ks[cur], c * 16 + l15, t2 * 4 + lg);
#pragma unroll
      for (int c = 0; c < 4; ++c) sacc[c] = mfma16(kf[c], qa[t2], sacc[c]);
    }
    __builtin_amdgcn_s_setprio(0);
    u64 sh = mskP >> (lg * 4);
    // refill alibi/mask for t+1 now — issues under the softmax VALU chain
#pragma unroll
    for (int c = 0; c < 4; ++c)
      albP[c] = *(const f32x4*)(arow + tn * 64 + c * 16);  // 4
    mskP = mrow[tn];                                       // 1

    // lane-local softmax over 16 k-values IN PLACE, cross-lg via 2 shfls
    float m16 = -__builtin_inff();
#pragma unroll
    for (int c = 0; c < 4; ++c) {
      unsigned bits = (unsigned)(sh >> (c * 16)) & 0xFu;
#pragma unroll
      for (int r = 0; r < 4; ++r) {
        float v = (bits & (1u << r)) ? sacc[c][r] : -1e9f;
        sacc[c][r] = v;
        m16 = fmaxf(m16, v);
      }
    }
    m16 = fmaxf(m16, __shfl_xor(m16, 16));
    m16 = fmaxf(m16, __shfl_xor(m16, 32));
    const bool norsc = __all(m16 <= mrun);  // exact: scl==1 for whole wave
    float mn = fmaxf(mrun, m16);
    float scl = __expf(mrun - mn);
    mrun = mn;
    float rs = 0.f;
#pragma unroll
    for (int c = 0; c < 4; ++c)
#pragma unroll
      for (int r = 0; r < 4; ++r) {
        float pe = __expf(sacc[c][r] - mn);
        sacc[c][r] = pe;
        rs += pe;
      }
    rs += __shfl_xor(rs, 16);
    rs += __shfl_xor(rs, 32);
    lrun = lrun * scl + rs;
    if (!norsc) {
#pragma unroll
      for (int c = 0; c < 4; ++c) {
        f32x4 v = cacc[c];
        v[0] *= scl; v[1] *= scl; v[2] *= scl; v[3] *= scl;
        cacc[c] = v;
      }
    }
    // P pack -> per-wave LDS (wave-local; compiler handles lgkmcnt)
#pragma unroll
    for (int c = 0; c < 4; ++c) {
      bf16x4 u;
#pragma unroll
      for (int r = 0; r < 4; ++r) u[r] = (__bf16)sacc[c][r];
      *(bf16x4*)(&Ps[wid][l15 * 72 + c * 16 + lg * 4]) = u;
    }
    __builtin_amdgcn_sched_barrier(0);
    // F: V(t) complete (6 newer: K(t+1) 1 + alibi 4 + mask 1)
    asm volatile("s_waitcnt vmcnt(6)" ::: "memory");
    __builtin_amdgcn_sched_barrier(0);
    __builtin_amdgcn_s_barrier();
    __builtin_amdgcn_sched_barrier(0);
    // PV swapped: cacc[c] += V^T-frag(d-block c) x P-frag
    __builtin_amdgcn_s_setprio(1);
#pragma unroll
    for (int t2 = 0; t2 < 2; ++t2) {
      bf16x8 pa = *(const bf16x8*)(&Ps[wid][l15 * 72 + t2 * 32 + lg * 8]);
#pragma unroll
      for (int c = 0; c < 4; ++c) {
        bf16x8 vb = read_frag(Vs, c * 16 + l15, t2 * 4 + lg);
        cacc[c] = mfma16(vb, pa, cacc[c]);
      }
    }
    __builtin_amdgcn_s_setprio(0);
  }
  // drain dangling prefetches (dummy last-tile stages + alibi/mask)
  asm volatile("s_waitcnt vmcnt(0)" ::: "memory");
  // epilogue: unnormalized partial O (bf16) + (m,l) per q-row
  __bf16* op = Op + (((size_t)z * 32 + bho) * S_LEN + q) * 64;
#pragma unroll
  for (int c = 0; c < 4; ++c) {
    bf16x4 u;
#pragma unroll
    for (int r = 0; r < 4; ++r) u[r] = (__bf16)cacc[c][r];
    *(bf16x4*)(op + c * 16 + lg * 4) = u;
  }
  if (lg == 0) {
    float2* mlp = (float2*)(ml + (((size_t)z * 32 + bho) * S_LEN + q) * 2);
    *mlp = make_float2(mrun, lrun);
  }
}

// ----------------------------------------------------------------- launch
extern "C" void kernel_launch(void* const* d_in, const int* in_sizes, int n_in,
                              void* d_out, int out_size, void* d_ws,
                              size_t ws_size, hipStream_t stream) {
  const float* x = (const float*)d_in[0];
  const int* mask = (const int*)d_in[1];
  const float* alibi = (const float*)d_in[2];
  const float* Wq = (const float*)d_in[3];
  const float* bq = (const float*)d_in[4];
  const float* Wk = (const float*)d_in[5];
  const float* bk = (const float*)d_in[6];
  const float* Wv = (const float*)d_in[7];
  const float* bv = (const float*)d_in[8];
  const float* Wo = (const float*)d_in[9];
  const float* bo = (const float*)d_in[10];
  float* out = (float*)d_out;
  char* ws = (char*)d_ws;

  const size_t MB = 1u << 20;
  __bf16* xb = (__bf16*)(ws);             // 8MB
  __bf16* wt = (__bf16*)(ws + 8 * MB);    // 8MB: Wq^T,Wk^T,Wv^T,Wo^T
  __bf16* Qb = (__bf16*)(ws + 16 * MB);   // 8MB
  __bf16* Kb = (__bf16*)(ws + 24 * MB);   // 8MB
  __bf16* VTb = (__bf16*)(ws + 32 * MB);  // 8MB: V^T written by GEMM
  u64* maskb = (u64*)(ws + 40 * MB);      // 1MB
  __bf16* Op = (__bf16*)(ws + 48 * MB);   // 16MB: bf16 partial O, 2 halves
  float* mlb = (float*)(ws + 72 * MB);    // 1MB: (m,l), 2 halves
  __bf16* wtq = wt;
  __bf16* wtk = wt + (1u << 20);
  __bf16* wtv = wt + 2 * (1u << 20);
  __bf16* wto = wt + 3 * (1u << 20);

  // one prep launch: x-convert (2048) + mask-pack (32768) + W^T (1024)
  k_prep<<<dim3(2048 + (2 * S_LEN * S_LEN) / 256 + 1024), 256, 0, stream>>>(
      x, xb, mask, maskb, Wq, Wk, Wv, Wo, wt);
  k_gemm<0><<<dim3(8, 32, 3), 256, 0, stream>>>(xb, wtq, wtk, wtv, bq, bk, bv,
                                                Qb, Kb, VTb, nullptr, nullptr,
                                                nullptr);
  k_attn<<<dim3(32, 16, 2), 512, 0, stream>>>(Qb, Kb, VTb, alibi, maskb, Op,
                                              mlb);
  k_gemm<1><<<dim3(8, 32, 1), 256, 0, stream>>>(nullptr, wto, nullptr, nullptr,
                                                bo, nullptr, nullptr, nullptr,
                                                nullptr, nullptr, out, Op, mlb);
}

// Round 22
// 225.988 us; speedup vs baseline: 1.0338x; 1.0338x over previous
//
#include <hip/hip_runtime.h>
#include <hip/hip_bf16.h>

// MultiHeadAttention: B=2, S=2048, H=1024, NH=16, DK=64
// R22 = R20 verbatim (measured best: 226.3 us, absmax 5.5e-4, replay-stable).
// Pipeline: k_prep (x->bf16 | mask->u64 bits | W->W^T bf16, one launch)
//   -> k_gemm<0> (QKV; Q pre-scaled 1/8; V^T written directly)
//   -> k_attn (KV-split x2, swapped-QK^T flash attention, in-place softmax,
//      XCD-paired alibi readers, two-barrier counted-vmcnt pipeline,
//      bf16 partial O + f32 (m,l))
//   -> k_combine (merge k-halves) -> k_gemm<1> (out-proj, f32 out).

#define S_LEN 2048
#define H_DIM 1024
#define N_HEADS 16

typedef __bf16 bf16x8 __attribute__((ext_vector_type(8)));
typedef __bf16 bf16x4 __attribute__((ext_vector_type(4)));
typedef float f32x4 __attribute__((ext_vector_type(4)));
typedef unsigned long long u64;

using gvoid = __attribute__((address_space(1))) void;
using svoid = __attribute__((address_space(3))) void;

static __device__ __forceinline__ f32x4 mfma16(bf16x8 a, bf16x8 b, f32x4 c) {
  return __builtin_amdgcn_mfma_f32_16x16x32_bf16(a, b, c, 0, 0, 0);
}

// Stage a [ROWS][64] bf16 tile into LDS via global_load_lds, 16B per lane.
// LDS: linear rows of 128B; 16B slot s holds global slot s^(r&7) (bank swizzle).
template <int NCH, int NW>
static __device__ __forceinline__ void stage64(const __bf16* g, int rstride,
                                               __bf16* lds, int wid, int lane) {
#pragma unroll
  for (int i = 0; i < NCH / NW; ++i) {
    int chunk = i * NW + wid;
    int u = chunk * 64 + lane;
    int r = u >> 3, s = u & 7;
    const __bf16* src = g + (size_t)r * rstride + ((s ^ (r & 7)) << 3);
    __builtin_amdgcn_global_load_lds((const gvoid*)src,
                                     (svoid*)(lds + chunk * 512), 16, 0, 0);
  }
}

static __device__ __forceinline__ bf16x8 read_frag(const __bf16* lds, int r,
                                                   int slot) {
  return *(const bf16x8*)(lds + r * 64 + ((slot ^ (r & 7)) << 3));
}

// ---------------- prep: x -> bf16 | mask -> u64 bits | W -> W^T bf16
__global__ __launch_bounds__(256) void k_prep(
    const float* __restrict__ x, __bf16* __restrict__ xb,
    const int* __restrict__ m, u64* __restrict__ mout,
    const float* __restrict__ w0, const float* __restrict__ w1,
    const float* __restrict__ w2, const float* __restrict__ w3,
    __bf16* __restrict__ wt) {
  int blk = blockIdx.x;
  if (blk < 2048) {
    size_t idx = ((size_t)blk * 256 + threadIdx.x) * 8;
    float4 a = *(const float4*)(x + idx);
    float4 b = *(const float4*)(x + idx + 4);
    bf16x8 o;
    o[0] = (__bf16)a.x; o[1] = (__bf16)a.y; o[2] = (__bf16)a.z; o[3] = (__bf16)a.w;
    o[4] = (__bf16)b.x; o[5] = (__bf16)b.y; o[6] = (__bf16)b.z; o[7] = (__bf16)b.w;
    *(bf16x8*)(xb + idx) = o;
  } else if (blk < 34816) {
    size_t idx = (size_t)(blk - 2048) * 256 + threadIdx.x;
    u64 b = __ballot(m[idx] != 0);
    if ((threadIdx.x & 63) == 0) mout[idx >> 6] = b;
  } else {
    __shared__ float t[64][65];
    int i = blk - 34816;
    int z = i >> 8;
    const float* W = (z == 0) ? w0 : (z == 1) ? w1 : (z == 2) ? w2 : w3;
    __bf16* O = wt + (size_t)z * H_DIM * H_DIM;
    int k0 = ((i >> 4) & 15) * 64, n0 = (i & 15) * 64;
    int tid = threadIdx.x;
    {
      int r = tid >> 4, c4 = tid & 15;
#pragma unroll
      for (int j = 0; j < 4; ++j) {
        float4 v =
            *(const float4*)(W + (size_t)(k0 + r + j * 16) * H_DIM + n0 + c4 * 4);
        t[r + j * 16][c4 * 4 + 0] = v.x;
        t[r + j * 16][c4 * 4 + 1] = v.y;
        t[r + j * 16][c4 * 4 + 2] = v.z;
        t[r + j * 16][c4 * 4 + 3] = v.w;
      }
    }
    __syncthreads();
    {
      int nn = tid >> 2, js = (tid & 3) * 16;
      bf16x8 o0, o1;
#pragma unroll
      for (int j = 0; j < 8; ++j) {
        o0[j] = (__bf16)t[js + j][nn];
        o1[j] = (__bf16)t[js + 8 + j][nn];
      }
      __bf16* dst = O + (size_t)(n0 + nn) * H_DIM + k0 + js;
      *(bf16x8*)dst = o0;
      *(bf16x8*)(dst + 8) = o1;
    }
  }
}

// ----------------------------------------------------------------- GEMMs
// MODE 0: C = xb . Wt^T + bias -> bf16; z==0 (Q, scaled 1/8) and z==1 (K)
//         write [b,h,s,d]; z==2 (V) writes V^T [b,h,d,s] directly.
// MODE 1: C = ctx . Wt_o^T + bias -> f32 out
template <int MODE>
__global__ __launch_bounds__(256) void k_gemm(
    const __bf16* __restrict__ A, const __bf16* __restrict__ B0,
    const __bf16* __restrict__ B1, const __bf16* __restrict__ B2,
    const float* __restrict__ bias0, const float* __restrict__ bias1,
    const float* __restrict__ bias2, __bf16* __restrict__ O0,
    __bf16* __restrict__ O1, __bf16* __restrict__ O2, float* __restrict__ Of) {
  __shared__ alignas(16) __bf16 As[128 * 64];
  __shared__ alignas(16) __bf16 Bs[128 * 64];
  int tid = threadIdx.x, wid = tid >> 6, lane = tid & 63;
  int l15 = lane & 15, lg = lane >> 4;
  int nbase = blockIdx.x * 128, mbase = blockIdx.y * 128;
  const __bf16* Bm;
  const float* bias;
  __bf16* Ob;
  float oscale = 1.0f;
  const int zv = (MODE == 0) ? blockIdx.z : 0;
  if (MODE == 0) {
    Bm = (zv == 0) ? B0 : (zv == 1) ? B1 : B2;
    bias = (zv == 0) ? bias0 : (zv == 1) ? bias1 : bias2;
    Ob = (zv == 0) ? O0 : (zv == 1) ? O1 : O2;
    if (zv == 0) oscale = 0.125f;
  } else {
    Bm = B0; bias = bias0; Ob = O0;
  }
  int wrow = wid >> 1, wcol = wid & 1;
  f32x4 zero = {0.f, 0.f, 0.f, 0.f};
  f32x4 acc[4][4];
#pragma unroll
  for (int i = 0; i < 4; ++i)
#pragma unroll
    for (int j = 0; j < 4; ++j) acc[i][j] = zero;

  for (int kb = 0; kb < H_DIM; kb += 64) {
    __syncthreads();
    const __bf16* Abase;
    int arstride;
    if (MODE == 0) {
      Abase = A + (size_t)mbase * H_DIM + kb;
      arstride = H_DIM;
    } else {
      int b = mbase >> 11, q0 = mbase & 2047, head = kb >> 6;
      Abase = A + ((size_t)(b * N_HEADS + head) * S_LEN + q0) * 64;
      arstride = 64;
    }
    stage64<16, 4>(Abase, arstride, As, wid, lane);
    stage64<16, 4>(Bm + (size_t)nbase * H_DIM + kb, H_DIM, Bs, wid, lane);
    __syncthreads();
#pragma unroll
    for (int t = 0; t < 2; ++t) {
      bf16x8 a[4], bfr[4];
#pragma unroll
      for (int i = 0; i < 4; ++i)
        a[i] = read_frag(As, wrow * 64 + i * 16 + l15, t * 4 + lg);
#pragma unroll
      for (int j = 0; j < 4; ++j)
        bfr[j] = read_frag(Bs, wcol * 64 + j * 16 + l15, t * 4 + lg);
#pragma unroll
      for (int i = 0; i < 4; ++i)
#pragma unroll
        for (int j = 0; j < 4; ++j) acc[i][j] = mfma16(a[i], bfr[j], acc[i][j]);
    }
  }
  float bv[4];
#pragma unroll
  for (int j = 0; j < 4; ++j) bv[j] = bias[nbase + wcol * 64 + j * 16 + l15];
#pragma unroll
  for (int i = 0; i < 4; ++i)
#pragma unroll
    for (int j = 0; j < 4; ++j) {
      if (MODE == 0 && zv == 2) {
        // V^T direct: the 4 r-values are 4 consecutive s at fixed col=d.
        int m0 = mbase + wrow * 64 + i * 16 + lg * 4;
        int col = nbase + wcol * 64 + j * 16 + l15;
        bf16x4 u;
#pragma unroll
        for (int r = 0; r < 4; ++r) u[r] = (__bf16)(acc[i][j][r] + bv[j]);
        size_t off =
            (((size_t)(m0 >> 11) * N_HEADS + (col >> 6)) * 64 + (col & 63)) *
                (size_t)S_LEN +
            (m0 & 2047);
        *(bf16x4*)(Ob + off) = u;
      } else {
#pragma unroll
        for (int r = 0; r < 4; ++r) {
          int m = mbase + wrow * 64 + i * 16 + lg * 4 + r;
          int col = nbase + wcol * 64 + j * 16 + l15;
          float v = (acc[i][j][r] + bv[j]) * oscale;
          if (MODE == 0) {
            size_t off =
                (((size_t)(m >> 11) * N_HEADS + (col >> 6)) * S_LEN +
                 (m & 2047)) *
                    64 +
                (col & 63);
            Ob[off] = (__bf16)v;
          } else {
            Of[(size_t)m * H_DIM + col] = v;
          }
        }
      }
    }
}

// ------------------------------------------------------------- attention
// KV-split x2, in-place softmax, XCD alibi pairing (b=bh>>4, h=bh&15).
// grid: (B*NH, S/128, 2); block 512 (8 waves). z picks k-half [z*1024,+1024).
// Two-barrier counted-vmcnt skeleton:
//   E: vmcnt(5) [K(t) done]; bar; stage V(t); stage K(t+1); QK^T (C-init
//   alibi); refill alibi/mask; softmax in place; P->Ps; F: vmcnt(6)
//   [V(t) done]; bar; PV(t). Emits bf16 partial O + f32 (m,l).
__global__ __launch_bounds__(512) void k_attn(
    const __bf16* __restrict__ Q, const __bf16* __restrict__ K,
    const __bf16* __restrict__ VT, const float* __restrict__ alibi,
    const u64* __restrict__ maskb, __bf16* __restrict__ Op,
    float* __restrict__ ml) {
  __shared__ alignas(16) __bf16 Ks[2][64 * 64];
  __shared__ alignas(16) __bf16 Vs[64 * 64];
  __shared__ alignas(16) __bf16 Ps[8][16 * 72];
  int tid = threadIdx.x, wid = tid >> 6, lane = tid & 63;
  int l15 = lane & 15, lg = lane >> 4;
  int bh = blockIdx.x;
  int b = bh >> 4, h = bh & 15;  // pair (b0,b1) of one h: x=h and x=h+16
  int qbase = blockIdx.y * 128;  // -> same XCD (x mod 8 equal), same rows
  const int z = blockIdx.z;
  size_t bho = (size_t)(b * N_HEADS + h);
  const __bf16* Qb = Q + bho * S_LEN * 64;
  const __bf16* Kbz = K + (bho * S_LEN + (size_t)z * 1024) * 64;
  const __bf16* Vbz = VT + bho * 64 * S_LEN + z * 1024;
  const int q = qbase + wid * 16 + l15;  // this lane's q row
  const int NT = 16;                     // 1024 k-positions per half

  bf16x8 qa[2];
  {
    const __bf16* qrow = Qb + (size_t)q * 64;
    qa[0] = *(const bf16x8*)(qrow + lg * 8);
    qa[1] = *(const bf16x8*)(qrow + 32 + lg * 8);
  }
  float mrun = -__builtin_inff(), lrun = 0.f;
  f32x4 cacc[4];  // O^T[d = c*16+lg*4+r][q = l15]
  f32x4 zero = {0.f, 0.f, 0.f, 0.f};
#pragma unroll
  for (int c = 0; c < 4; ++c) cacc[c] = zero;

  const float* arow =
      alibi + ((size_t)h * S_LEN + q) * S_LEN + z * 1024 + lg * 4;
  const u64* mrow =
      maskb + ((size_t)b * S_LEN + q) * (S_LEN / 64) + z * 16;

  // ---- prologue: K(0) stage, alibi(0)+mask(0) regs (order pinned) ----
  stage64<8, 8>(Kbz, 64, Ks[0], wid, lane);  // 1 gl_lds
  __builtin_amdgcn_sched_barrier(0);
  f32x4 albP[4];
  u64 mskP;
#pragma unroll
  for (int c = 0; c < 4; ++c) albP[c] = *(const f32x4*)(arow + c * 16);  // 4
  mskP = mrow[0];                                                        // 1
  __builtin_amdgcn_sched_barrier(0);

  for (int t = 0; t < NT; ++t) {
    const int cur = t & 1;
    // E: K(t) complete (5 newer in flight: alibi(t) 4 + mask(t) 1)
    asm volatile("s_waitcnt vmcnt(5)" ::: "memory");
    __builtin_amdgcn_sched_barrier(0);
    __builtin_amdgcn_s_barrier();
    __builtin_amdgcn_sched_barrier(0);
    // A: stage V(t) (consumed after F this phase; Vs free since barrier)
    stage64<8, 8>(Vbz + t * 64, S_LEN, Vs, wid, lane);  // 1
    __builtin_amdgcn_sched_barrier(0);
    // B: stage K(t+1) into alternate buffer (clamped at the end)
    const int tn = (t + 1 < NT) ? t + 1 : t;
    stage64<8, 8>(Kbz + (size_t)tn * 64 * 64, 64, Ks[cur ^ 1], wid, lane);  // 1
    __builtin_amdgcn_sched_barrier(0);

    // QK^T swapped: sacc[c][r] = S[k=c*16+lg*4+r][q=l15] + alibi (C-init).
    // (Q pre-scaled by 1/8 in the QKV GEMM epilogue.)
    f32x4 sacc[4];
#pragma unroll
    for (int c = 0; c < 4; ++c) sacc[c] = albP[c];
    __builtin_amdgcn_s_setprio(1);
#pragma unroll
    for (int t2 = 0; t2 < 2; ++t2) {
      bf16x8 kf[4];
#pragma unroll
      for (int c = 0; c < 4; ++c)
        kf[c] = read_frag(Ks[cur], c * 16 + l15, t2 * 4 + lg);
#pragma unroll
      for (int c = 0; c < 4; ++c) sacc[c] = mfma16(kf[c], qa[t2], sacc[c]);
    }
    __builtin_amdgcn_s_setprio(0);
    u64 sh = mskP >> (lg * 4);
    // refill alibi/mask for t+1 now — issues under the softmax VALU chain
#pragma unroll
    for (int c = 0; c < 4; ++c)
      albP[c] = *(const f32x4*)(arow + tn * 64 + c * 16);  // 4
    mskP = mrow[tn];                                       // 1

    // lane-local softmax over 16 k-values IN PLACE, cross-lg via 2 shfls
    float m16 = -__builtin_inff();
#pragma unroll
    for (int c = 0; c < 4; ++c) {
      unsigned bits = (unsigned)(sh >> (c * 16)) & 0xFu;
#pragma unroll
      for (int r = 0; r < 4; ++r) {
        float v = (bits & (1u << r)) ? sacc[c][r] : -1e9f;
        sacc[c][r] = v;
        m16 = fmaxf(m16, v);
      }
    }
    m16 = fmaxf(m16, __shfl_xor(m16, 16));
    m16 = fmaxf(m16, __shfl_xor(m16, 32));
    const bool norsc = __all(m16 <= mrun);  // exact: scl==1 for whole wave
    float mn = fmaxf(mrun, m16);
    float scl = __expf(mrun - mn);
    mrun = mn;
    float rs = 0.f;
#pragma unroll
    for (int c = 0; c < 4; ++c)
#pragma unroll
      for (int r = 0; r < 4; ++r) {
        float pe = __expf(sacc[c][r] - mn);
        sacc[c][r] = pe;
        rs += pe;
      }
    rs += __shfl_xor(rs, 16);
    rs += __shfl_xor(rs, 32);
    lrun = lrun * scl + rs;
    if (!norsc) {
#pragma unroll
      for (int c = 0; c < 4; ++c) {
        f32x4 v = cacc[c];
        v[0] *= scl; v[1] *= scl; v[2] *= scl; v[3] *= scl;
        cacc[c] = v;
      }
    }
    // P pack -> per-wave LDS (wave-local; compiler handles lgkmcnt)
#pragma unroll
    for (int c = 0; c < 4; ++c) {
      bf16x4 u;
#pragma unroll
      for (int r = 0; r < 4; ++r) u[r] = (__bf16)sacc[c][r];
      *(bf16x4*)(&Ps[wid][l15 * 72 + c * 16 + lg * 4]) = u;
    }
    __builtin_amdgcn_sched_barrier(0);
    // F: V(t) complete (6 newer: K(t+1) 1 + alibi 4 + mask 1)
    asm volatile("s_waitcnt vmcnt(6)" ::: "memory");
    __builtin_amdgcn_sched_barrier(0);
    __builtin_amdgcn_s_barrier();
    __builtin_amdgcn_sched_barrier(0);
    // PV swapped: cacc[c] += V^T-frag(d-block c) x P-frag
    __builtin_amdgcn_s_setprio(1);
#pragma unroll
    for (int t2 = 0; t2 < 2; ++t2) {
      bf16x8 pa = *(const bf16x8*)(&Ps[wid][l15 * 72 + t2 * 32 + lg * 8]);
#pragma unroll
      for (int c = 0; c < 4; ++c) {
        bf16x8 vb = read_frag(Vs, c * 16 + l15, t2 * 4 + lg);
        cacc[c] = mfma16(vb, pa, cacc[c]);
      }
    }
    __builtin_amdgcn_s_setprio(0);
  }
  // drain dangling prefetches (dummy last-tile stages + alibi/mask)
  asm volatile("s_waitcnt vmcnt(0)" ::: "memory");
  // epilogue: unnormalized partial O (bf16) + (m,l) per q-row
  __bf16* op = Op + (((size_t)z * 32 + bho) * S_LEN + q) * 64;
#pragma unroll
  for (int c = 0; c < 4; ++c) {
    bf16x4 u;
#pragma unroll
    for (int r = 0; r < 4; ++r) u[r] = (__bf16)cacc[c][r];
    *(bf16x4*)(op + c * 16 + lg * 4) = u;
  }
  if (lg == 0) {
    float2* mlp = (float2*)(ml + (((size_t)z * 32 + bho) * S_LEN + q) * 2);
    *mlp = make_float2(mrun, lrun);
  }
}

// --------------------------------------------- combine the two k-halves
// Op: [2][32][2048][64] bf16, ml: [2][32][2048][2] f32 -> ctx bf16
__global__ __launch_bounds__(256) void k_combine(const __bf16* __restrict__ Op,
                                                 const float* __restrict__ ml,
                                                 __bf16* __restrict__ ctx) {
  int t = blockIdx.x * 256 + threadIdx.x;
  int dgrp = t & 15, qq = t >> 4;  // qq in [0, 65536)
  float2 m0 = *(const float2*)(ml + (size_t)qq * 2);
  float2 m1 = *(const float2*)(ml + ((size_t)65536 + qq) * 2);
  float m = fmaxf(m0.x, m1.x);
  float e0 = __expf(m0.x - m), e1 = __expf(m1.x - m);
  float inv = 1.f / (m0.y * e0 + m1.y * e1);
  bf16x4 a = *(const bf16x4*)(Op + (size_t)qq * 64 + dgrp * 4);
  bf16x4 c = *(const bf16x4*)(Op + (size_t)65536 * 64 + (size_t)qq * 64 + dgrp * 4);
  bf16x4 o;
#pragma unroll
  for (int j = 0; j < 4; ++j)
    o[j] = (__bf16)(((float)a[j] * e0 + (float)c[j] * e1) * inv);
  *(bf16x4*)(ctx + (size_t)qq * 64 + dgrp * 4) = o;
}

// ----------------------------------------------------------------- launch
extern "C" void kernel_launch(void* const* d_in, const int* in_sizes, int n_in,
                              void* d_out, int out_size, void* d_ws,
                              size_t ws_size, hipStream_t stream) {
  const float* x = (const float*)d_in[0];
  const int* mask = (const int*)d_in[1];
  const float* alibi = (const float*)d_in[2];
  const float* Wq = (const float*)d_in[3];
  const float* bq = (const float*)d_in[4];
  const float* Wk = (const float*)d_in[5];
  const float* bk = (const float*)d_in[6];
  const float* Wv = (const float*)d_in[7];
  const float* bv = (const float*)d_in[8];
  const float* Wo = (const float*)d_in[9];
  const float* bo = (const float*)d_in[10];
  float* out = (float*)d_out;
  char* ws = (char*)d_ws;

  const size_t MB = 1u << 20;
  __bf16* xb = (__bf16*)(ws);             // 8MB (reused as ctx later)
  __bf16* wt = (__bf16*)(ws + 8 * MB);    // 8MB: Wq^T,Wk^T,Wv^T,Wo^T
  __bf16* Qb = (__bf16*)(ws + 16 * MB);   // 8MB
  __bf16* Kb = (__bf16*)(ws + 24 * MB);   // 8MB
  __bf16* VTb = (__bf16*)(ws + 32 * MB);  // 8MB: V^T written by GEMM
  u64* maskb = (u64*)(ws + 40 * MB);      // 1MB
  __bf16* Op = (__bf16*)(ws + 48 * MB);   // 16MB: bf16 partial O, 2 halves
  float* mlb = (float*)(ws + 72 * MB);    // 1MB: (m,l), 2 halves
  __bf16* ctxb = xb;
  __bf16* wtq = wt;
  __bf16* wtk = wt + (1u << 20);
  __bf16* wtv = wt + 2 * (1u << 20);
  __bf16* wto = wt + 3 * (1u << 20);

  // one prep launch: x-convert (2048) + mask-pack (32768) + W^T (1024)
  k_prep<<<dim3(2048 + (2 * S_LEN * S_LEN) / 256 + 1024), 256, 0, stream>>>(
      x, xb, mask, maskb, Wq, Wk, Wv, Wo, wt);
  k_gemm<0><<<dim3(8, 32, 3), 256, 0, stream>>>(xb, wtq, wtk, wtv, bq, bk, bv,
                                                Qb, Kb, VTb, nullptr);
  k_attn<<<dim3(32, 16, 2), 512, 0, stream>>>(Qb, Kb, VTb, alibi, maskb, Op,
                                              mlb);
  k_combine<<<dim3(4096), 256, 0, stream>>>(Op, mlb, ctxb);
  k_gemm<1><<<dim3(8, 32, 1), 256, 0, stream>>>(ctxb, wto, nullptr, nullptr, bo,
                                                nullptr, nullptr, nullptr,
                                                nullptr, nullptr, out);
}